// Round 5
// baseline (403.621 us; speedup 1.0000x reference)
//
#include <hip/hip_runtime.h>
#include <math.h>

// Problem constants
#define NB 2
#define SEQ 2048
#define HDIM 2048
#define NHD 16
#define NKVH 4
#define HEADD 128
#define MROWS (NB*SEQ)          // 4096
#define NQCOLS (NHD*HEADD)      // 2048
#define QKVCOLS 3072            // fused Q (2048) + K (512) + V (512)

typedef unsigned short ushortT;
typedef __attribute__((ext_vector_type(8))) short short8;
typedef __attribute__((ext_vector_type(4))) float floatx4;
typedef __attribute__((ext_vector_type(4))) unsigned short ushort4v;

__device__ __forceinline__ ushortT f2bf(float f) {
  union { float f; unsigned int u; } v; v.f = f;
  unsigned int r = v.u + 0x7FFFu + ((v.u >> 16) & 1u);
  return (ushortT)(r >> 16);
}
__device__ __forceinline__ float bf2f(ushortT u) {
  union { unsigned int u; float f; } v; v.u = ((unsigned int)u) << 16;
  return v.f;
}

// async global->LDS, 16B per lane (LDS dest = wave-uniform base + lane*16).
__device__ __forceinline__ void gload16(const ushortT* g, ushortT* l) {
  __builtin_amdgcn_global_load_lds(
      (const __attribute__((address_space(1))) void*)g,
      (__attribute__((address_space(3))) void*)l, 16, 0, 0);
}

// ---------------- cast fp32 -> bf16 (vectorized) ----------------
__global__ __launch_bounds__(256) void cast_bf16_kernel(
    const float* __restrict__ in, ushortT* __restrict__ out, int n4) {
  int i = blockIdx.x * 256 + threadIdx.x;
  if (i >= n4) return;
  float4 v = ((const float4*)in)[i];
  ushort4v o;
  o.x = f2bf(v.x); o.y = f2bf(v.y); o.z = f2bf(v.z); o.w = f2bf(v.w);
  ((ushort4v*)out)[i] = o;
}

// ---------------- transpose + cast: fp32 (R,C) -> bf16 (C,R) ----------------
__global__ __launch_bounds__(256) void transpose_cast_kernel(
    const float* __restrict__ in, ushortT* __restrict__ out, int R, int C) {
  __shared__ ushortT tile[32][33];
  int c0 = blockIdx.x * 32, r0 = blockIdx.y * 32;
  int tx = threadIdx.x & 31, ty = threadIdx.x >> 5;  // ty 0..7
#pragma unroll
  for (int i = 0; i < 4; ++i)
    tile[ty + i*8][tx] = f2bf(in[(size_t)(r0 + ty + i*8) * C + c0 + tx]);
  __syncthreads();
#pragma unroll
  for (int i = 0; i < 4; ++i)
    out[(size_t)(c0 + ty + i*8) * R + r0 + tx] = tile[tx][ty + i*8];
}

// ---------------- GEMM: C(MxN) = A(MxK) * Bt(NxK)^T, bf16 in, bf16/fp32 out ----
// 128x128 tile, BK=64, 4 waves (2x2 of 64x64), mfma 16x16x32 bf16.
// global_load_lds width-16 staging, unpadded LDS, global-side XOR swizzle.
__global__ __launch_bounds__(256) void gemm_bt_kernel(
    const ushortT* __restrict__ A, const ushortT* __restrict__ Bt,
    void* __restrict__ C, int M, int N, int K, int c_fp32) {
  __shared__ __align__(16) ushortT lA[128 * 64];
  __shared__ __align__(16) ushortT lB[128 * 64];
  const int m0 = blockIdx.y * 128;
  const int n0 = blockIdx.x * 128;
  const int tid = threadIdx.x;
  const int wave = tid >> 6, lane = tid & 63;
  const int g = lane >> 4, l15 = lane & 15;
  const int wm = (wave >> 1) * 64, wn = (wave & 1) * 64;
  const int sw = l15 & 7;

  floatx4 acc[4][4] = {};

  for (int kt = 0; kt < K; kt += 64) {
    __syncthreads();
#pragma unroll
    for (int i = 0; i < 4; ++i) {
      int s = i * 256 + tid;
      int r = s >> 3, j = s & 7;
      int col8 = j ^ (r & 7);
      gload16(A  + (size_t)(m0 + r) * K + kt + col8 * 8, lA + s * 8);
      gload16(Bt + (size_t)(n0 + r) * K + kt + col8 * 8, lB + s * 8);
    }
    __syncthreads();
#pragma unroll
    for (int ks = 0; ks < 2; ++ks) {
      short8 af[4], bfv[4];
#pragma unroll
      for (int t = 0; t < 4; ++t) {
        af[t]  = *(const short8*)(lA + (wm + t * 16 + l15) * 64 + ((ks * 4 + g) ^ sw) * 8);
        bfv[t] = *(const short8*)(lB + (wn + t * 16 + l15) * 64 + ((ks * 4 + g) ^ sw) * 8);
      }
#pragma unroll
      for (int mt = 0; mt < 4; ++mt)
#pragma unroll
        for (int nt = 0; nt < 4; ++nt)
          acc[mt][nt] = __builtin_amdgcn_mfma_f32_16x16x32_bf16(
              af[mt], bfv[nt], acc[mt][nt], 0, 0, 0);
    }
  }

#pragma unroll
  for (int mt = 0; mt < 4; ++mt)
#pragma unroll
    for (int nt = 0; nt < 4; ++nt)
#pragma unroll
      for (int r = 0; r < 4; ++r) {
        int row = m0 + wm + mt * 16 + g * 4 + r;
        int col = n0 + wn + nt * 16 + l15;
        float v = acc[mt][nt][r];
        if (c_fp32) ((float*)C)[(size_t)row * N + col] = v;
        else ((ushortT*)C)[(size_t)row * N + col] = f2bf(v);
      }
}

// ---------------- RoPE Q: QKVtmp cols [0,2048) -> (B,NH,S,HD) bf16 -------------
__global__ __launch_bounds__(256) void rope_q_kernel(
    const ushortT* __restrict__ QKVtmp, const float* __restrict__ cosT,
    const float* __restrict__ sinT, ushortT* __restrict__ Qr) {
  int idx = blockIdx.x * 256 + threadIdx.x;   // B*S*NH*64 total
  int d = idx & 63;
  int t = idx >> 6;          // (b*S+s)*NH + h
  int h = t & (NHD - 1);
  int bs = t >> 4;           // b*S + s
  int s = bs & (SEQ - 1);
  int b = bs >> 11;
  float c = cosT[s * HEADD + d], sn = sinT[s * HEADD + d];
  float q1 = bf2f(QKVtmp[(size_t)bs * QKVCOLS + h * HEADD + d]);
  float q2 = bf2f(QKVtmp[(size_t)bs * QKVCOLS + h * HEADD + d + 64]);
  size_t o = ((size_t)(b * NHD + h) * SEQ + s) * HEADD + d;
  Qr[o]      = f2bf(q1 * c - q2 * sn);
  Qr[o + 64] = f2bf(q2 * c + q1 * sn);
}

// ---------------- RoPE K: QKVtmp cols [2048,2560) -> (B,NKV,S,HD) bf16 ---------
__global__ __launch_bounds__(256) void rope_k_kernel(
    const ushortT* __restrict__ QKVtmp, const float* __restrict__ cosT,
    const float* __restrict__ sinT, ushortT* __restrict__ Kr) {
  int idx = blockIdx.x * 256 + threadIdx.x;   // B*S*NKV*64 total
  int d = idx & 63;
  int t = idx >> 6;          // (b*S+s)*NKV + kvh
  int kvh = t & (NKVH - 1);
  int bs = t >> 2;
  int s = bs & (SEQ - 1);
  int b = bs >> 11;
  float c = cosT[s * HEADD + d], sn = sinT[s * HEADD + d];
  float k1 = bf2f(QKVtmp[(size_t)bs * QKVCOLS + 2048 + kvh * HEADD + d]);
  float k2 = bf2f(QKVtmp[(size_t)bs * QKVCOLS + 2048 + kvh * HEADD + d + 64]);
  size_t o = ((size_t)(b * NKVH + kvh) * SEQ + s) * HEADD + d;
  Kr[o]      = f2bf(k1 * c - k2 * sn);
  Kr[o + 64] = f2bf(k2 * c + k1 * sn);
}

// ---------------- V relayout: QKVtmp cols [2560,3072) -> (B,NKV,HD,S) ----------
__global__ __launch_bounds__(256) void v_relayout_kernel(
    const ushortT* __restrict__ QKVtmp, ushortT* __restrict__ Vt) {
  __shared__ ushortT tile[32][33];
  int bk = blockIdx.z;             // b*NKV + kvh
  int b = bk >> 2, kvh = bk & 3;
  int s0 = blockIdx.x * 32, d0 = blockIdx.y * 32;
  int tx = threadIdx.x & 31, ty = threadIdx.x >> 5;
#pragma unroll
  for (int i = 0; i < 4; ++i) {
    int s = s0 + ty + i * 8;
    tile[ty + i * 8][tx] =
        QKVtmp[(size_t)(b * SEQ + s) * QKVCOLS + 2560 + kvh * HEADD + d0 + tx];
  }
  __syncthreads();
#pragma unroll
  for (int i = 0; i < 4; ++i) {
    int d = d0 + ty + i * 8;
    Vt[((size_t)bk * HEADD + d) * SEQ + s0 + tx] = tile[tx][ty + i * 8];
  }
}

// ---------------- Flash attention (causal, GQA), BARRIER-FREE ------------------
// grid (32=bh fast, 16=paired q-block), 4 waves/block, each wave owns 32 q-rows.
// K/V fragments are read DIRECTLY from global (L1/L2-resident: K+V = 8 MB
// total, FETCH counter showed only ~31 MB HBM) -> no LDS staging, no
// __syncthreads in the K-loop. The only LDS is the per-wave P C->B-operand
// round-trip, which is wave-ordered (lgkmcnt) and needs no barrier.
// Scores computed transposed (S^T = K.Q^T): softmax over keys is in-lane
// (16 vals) + 2 shuffles; O^T = V^T.P^T.
__global__ __launch_bounds__(256, 2) void attn_kernel(
    const ushortT* __restrict__ Q,   // (B,NH,S,HD)
    const ushortT* __restrict__ Kg,  // (B,NKV,S,HD)
    const ushortT* __restrict__ Vg,  // (B,NKV,HD,S)
    ushortT* __restrict__ Oa) {      // (B,S,NH*HD)
  __shared__ __align__(16) ushortT lP[4 * 32 * 72]; // per-wave P (q x k), pad 72

  const int tid = threadIdx.x;
  const int w = tid >> 6, lane = tid & 63;
  const int g = lane >> 4, l15 = lane & 15;
  const int bh = blockIdx.x;
  const int b = bh >> 4, h = bh & 15;
  const int kvh = h >> 2;
  const int yi = blockIdx.y;
  const int qi = (yi < 8) ? (15 - yi) : (yi - 8);  // paired: CU gets 34 iters
  const int q0 = qi << 7;
  const int qw = q0 + w * 32;

  const float SC = 0.08838834764831845f * 1.4426950408889634f; // 1/sqrt(128)*log2e

  short8 qf[2][4];   // B-operand fragments of Q (q = qw + mt*16 + l15)
#pragma unroll
  for (int mt = 0; mt < 2; ++mt) {
    const ushortT* qp =
        Q + (((size_t)(b * NHD + h)) * SEQ + qw + mt * 16 + l15) * HEADD + g * 8;
#pragma unroll
    for (int ks = 0; ks < 4; ++ks) qf[mt][ks] = *(const short8*)(qp + ks * 32);
  }

  floatx4 o[2][8] = {};                       // O^T: col=q(l15), row=d(g*4+r)
  float m_s[2] = {-INFINITY, -INFINITY};
  float l_s[2] = {0.f, 0.f};

  const ushortT* kbase = Kg + ((size_t)(b * NKVH + kvh)) * SEQ * HEADD;
  const ushortT* vbase = Vg + ((size_t)(b * NKVH + kvh)) * HEADD * SEQ;
  ushortT* pw = lP + w * 32 * 72;

  // waves 0,1 (lower q-halves) never touch the last k-tile of the block
  const int nkt = 2 * qi + 2 - (w < 2 ? 1 : 0);
  for (int kt = 0; kt < nkt; ++kt) {
    // S^T = K . Q^T : A = K fragment straight from global (row=key, 64B runs)
    const ushortT* kp = kbase + (size_t)kt * 64 * HEADD;
    floatx4 sc[2][4] = {};
#pragma unroll
    for (int ks = 0; ks < 4; ++ks)
#pragma unroll
      for (int nt = 0; nt < 4; ++nt) {
        short8 kf = *(const short8*)(kp + (size_t)(nt * 16 + l15) * HEADD + ks * 32 + g * 8);
        sc[0][nt] = __builtin_amdgcn_mfma_f32_16x16x32_bf16(kf, qf[0][ks], sc[0][nt], 0, 0, 0);
        sc[1][nt] = __builtin_amdgcn_mfma_f32_16x16x32_bf16(kf, qf[1][ks], sc[1][nt], 0, 0, 0);
      }

#pragma unroll
    for (int mt = 0; mt < 2; ++mt) {
      const int qsub = qw + mt * 16;               // + l15 per lane
      const bool needmask = (kt * 64 + 63) > qsub; // wave-uniform
      float ps[4][4];
      float mx = -INFINITY;
#pragma unroll
      for (int nt = 0; nt < 4; ++nt)
#pragma unroll
        for (int r = 0; r < 4; ++r) {
          float v = sc[mt][nt][r] * SC;
          if (needmask) {
            int kg = kt * 64 + nt * 16 + g * 4 + r;
            if (kg > qsub + l15) v = -INFINITY;
          }
          ps[nt][r] = v;
          mx = fmaxf(mx, v);
        }
      mx = fmaxf(mx, __shfl_xor(mx, 16));
      mx = fmaxf(mx, __shfl_xor(mx, 32));
      float mn = fmaxf(m_s[mt], mx);
      float alpha = __builtin_amdgcn_exp2f(m_s[mt] - mn);
      m_s[mt] = mn;
      float rs = 0.f;
#pragma unroll
      for (int nt = 0; nt < 4; ++nt) {
        ushort4v pk;
#pragma unroll
        for (int r = 0; r < 4; ++r) {
          float e = __builtin_amdgcn_exp2f(ps[nt][r] - mn);
          rs += e;
          ((ushortT*)&pk)[r] = f2bf(e);
        }
        // P[q_local][k]: row = mt*16+l15, k = nt*16 + g*4 .. +3 (b64 write)
        *(ushort4v*)(pw + (mt * 16 + l15) * 72 + nt * 16 + g * 4) = pk;
      }
      rs += __shfl_xor(rs, 16);
      rs += __shfl_xor(rs, 32);
      l_s[mt] = l_s[mt] * alpha + rs;
#pragma unroll
      for (int dt = 0; dt < 8; ++dt)
#pragma unroll
        for (int r = 0; r < 4; ++r) o[mt][dt][r] *= alpha;
    }

    // O^T += V^T . P^T  (A = V^T fragment straight from global, B = P^T)
#pragma unroll
    for (int ks = 0; ks < 2; ++ks) {
      short8 bp0 = *(const short8*)(pw + l15 * 72 + ks * 32 + g * 8);
      short8 bp1 = *(const short8*)(pw + (16 + l15) * 72 + ks * 32 + g * 8);
#pragma unroll
      for (int dt = 0; dt < 8; ++dt) {
        short8 vf = *(const short8*)(vbase + (size_t)(dt * 16 + l15) * SEQ +
                                     kt * 64 + ks * 32 + g * 8);
        o[0][dt] = __builtin_amdgcn_mfma_f32_16x16x32_bf16(vf, bp0, o[0][dt], 0, 0, 0);
        o[1][dt] = __builtin_amdgcn_mfma_f32_16x16x32_bf16(vf, bp1, o[1][dt], 0, 0, 0);
      }
    }
  }

  // epilogue: O^T -> Oa (B,S,NH*HD); q = qw+mt*16+l15, d = dt*16+g*4+r
#pragma unroll
  for (int mt = 0; mt < 2; ++mt) {
    float inv = 1.f / l_s[mt];
    int qg = qw + mt * 16 + l15;
#pragma unroll
    for (int dt = 0; dt < 8; ++dt) {
      ushort4v ov;
#pragma unroll
      for (int r = 0; r < 4; ++r) ((ushortT*)&ov)[r] = f2bf(o[mt][dt][r] * inv);
      *(ushort4v*)(Oa + (size_t)(b * SEQ + qg) * NQCOLS + h * HEADD + dt * 16 + g * 4) = ov;
    }
  }
}

extern "C" void kernel_launch(void* const* d_in, const int* in_sizes, int n_in,
                              void* d_out, int out_size, void* d_ws, size_t ws_size,
                              hipStream_t stream) {
  const float* x    = (const float*)d_in[0];
  const float* cosT = (const float*)d_in[1];
  const float* sinT = (const float*)d_in[2];
  const float* Wq   = (const float*)d_in[3];
  const float* Wkv  = (const float*)d_in[4];
  const float* Wo   = (const float*)d_in[5];

  char* ws = (char*)d_ws;
  // workspace layout (bytes)
  ushortT* x_bf   = (ushortT*)(ws + 0);          // 16777216
  ushortT* Wqkvt  = (ushortT*)(ws + 16777216);   // 12582912 (3072 x 2048 bf16)
  ushortT* Wot    = (ushortT*)(ws + 29360128);   //  8388608
  ushortT* QKVtmp = (ushortT*)(ws + 37748736);   // 25165824 (4096 x 3072 bf16)
  ushortT* Qr     = (ushortT*)(ws + 62914560);   // 16777216
  ushortT* Kr     = (ushortT*)(ws + 79691776);   //  4194304
  ushortT* Vt     = (ushortT*)(ws + 83886080);   //  4194304
  ushortT* Oattn  = QKVtmp;                      // alias; total 88080384

  // 1) casts / weight transposes (Wq|Wkv stacked into one N x K operand)
  cast_bf16_kernel<<<8192, 256, 0, stream>>>(x, x_bf, (MROWS * HDIM) / 4);
  transpose_cast_kernel<<<dim3(64, 64), 256, 0, stream>>>(Wq, Wqkvt, HDIM, NQCOLS);
  transpose_cast_kernel<<<dim3(32, 64), 256, 0, stream>>>(Wkv, Wqkvt + 2048 * 2048, HDIM, 1024);
  transpose_cast_kernel<<<dim3(64, 64), 256, 0, stream>>>(Wo, Wot, NQCOLS, HDIM);

  // 2) fused QKV projection: (4096 x 2048) x (2048 x 3072) -> 768 blocks, 3/CU
  gemm_bt_kernel<<<dim3(24, 32), 256, 0, stream>>>(x_bf, Wqkvt, QKVtmp, MROWS, QKVCOLS, HDIM, 0);

  // 3) rope + relayout
  rope_q_kernel<<<16384, 256, 0, stream>>>(QKVtmp, cosT, sinT, Qr);
  rope_k_kernel<<<4096, 256, 0, stream>>>(QKVtmp, cosT, sinT, Kr);
  v_relayout_kernel<<<dim3(64, 4, 8), 256, 0, stream>>>(QKVtmp, Vt);

  // 4) attention (barrier-free; 512 blocks, paired long+short per CU)
  attn_kernel<<<dim3(32, 16), 256, 0, stream>>>(Qr, Kr, Vt, Oattn);

  // 5) output projection (fp32 out)
  gemm_bt_kernel<<<dim3(16, 32), 256, 0, stream>>>(Oattn, Wot, d_out, MROWS, HDIM, NQCOLS, 1);
}

// Round 6
// 401.769 us; speedup vs baseline: 1.0046x; 1.0046x over previous
//
#include <hip/hip_runtime.h>
#include <math.h>

// Problem constants
#define NB 2
#define SEQ 2048
#define HDIM 2048
#define NHD 16
#define NKVH 4
#define HEADD 128
#define MROWS (NB*SEQ)          // 4096
#define NQCOLS (NHD*HEADD)      // 2048
#define QKVCOLS 3072            // fused Q (2048) + K (512) + V (512)

typedef unsigned short ushortT;
typedef __attribute__((ext_vector_type(8))) short short8;
typedef __attribute__((ext_vector_type(4))) float floatx4;
typedef __attribute__((ext_vector_type(4))) unsigned short ushort4v;

__device__ __forceinline__ ushortT f2bf(float f) {
  union { float f; unsigned int u; } v; v.f = f;
  unsigned int r = v.u + 0x7FFFu + ((v.u >> 16) & 1u);
  return (ushortT)(r >> 16);
}
__device__ __forceinline__ float bf2f(ushortT u) {
  union { unsigned int u; float f; } v; v.u = ((unsigned int)u) << 16;
  return v.f;
}

// async global->LDS, 16B per lane (LDS dest = wave-uniform base + lane*16).
__device__ __forceinline__ void gload16(const ushortT* g, ushortT* l) {
  __builtin_amdgcn_global_load_lds(
      (const __attribute__((address_space(1))) void*)g,
      (__attribute__((address_space(3))) void*)l, 16, 0, 0);
}

// ---------------- cast fp32 -> bf16 (vectorized) ----------------
__global__ __launch_bounds__(256) void cast_bf16_kernel(
    const float* __restrict__ in, ushortT* __restrict__ out, int n4) {
  int i = blockIdx.x * 256 + threadIdx.x;
  if (i >= n4) return;
  float4 v = ((const float4*)in)[i];
  ushort4v o;
  o.x = f2bf(v.x); o.y = f2bf(v.y); o.z = f2bf(v.z); o.w = f2bf(v.w);
  ((ushort4v*)out)[i] = o;
}

// ---------------- transpose + cast: fp32 (R,C) -> bf16 (C,R) ----------------
__global__ __launch_bounds__(256) void transpose_cast_kernel(
    const float* __restrict__ in, ushortT* __restrict__ out, int R, int C) {
  __shared__ ushortT tile[32][33];
  int c0 = blockIdx.x * 32, r0 = blockIdx.y * 32;
  int tx = threadIdx.x & 31, ty = threadIdx.x >> 5;  // ty 0..7
#pragma unroll
  for (int i = 0; i < 4; ++i)
    tile[ty + i*8][tx] = f2bf(in[(size_t)(r0 + ty + i*8) * C + c0 + tx]);
  __syncthreads();
#pragma unroll
  for (int i = 0; i < 4; ++i)
    out[(size_t)(c0 + ty + i*8) * R + r0 + tx] = tile[tx][ty + i*8];
}

// ---------------- GEMM: C(MxN) = A(MxK) * Bt(NxK)^T, bf16 in, bf16/fp32 out ----
// 128x128 tile, BK=64, 4 waves (2x2 of 64x64), mfma 16x16x32 bf16.
// global_load_lds width-16 staging, unpadded LDS, global-side XOR swizzle.
__global__ __launch_bounds__(256) void gemm_bt_kernel(
    const ushortT* __restrict__ A, const ushortT* __restrict__ Bt,
    void* __restrict__ C, int M, int N, int K, int c_fp32) {
  __shared__ __align__(16) ushortT lA[128 * 64];
  __shared__ __align__(16) ushortT lB[128 * 64];
  const int m0 = blockIdx.y * 128;
  const int n0 = blockIdx.x * 128;
  const int tid = threadIdx.x;
  const int wave = tid >> 6, lane = tid & 63;
  const int g = lane >> 4, l15 = lane & 15;
  const int wm = (wave >> 1) * 64, wn = (wave & 1) * 64;
  const int sw = l15 & 7;

  floatx4 acc[4][4] = {};

  for (int kt = 0; kt < K; kt += 64) {
    __syncthreads();
#pragma unroll
    for (int i = 0; i < 4; ++i) {
      int s = i * 256 + tid;
      int r = s >> 3, j = s & 7;
      int col8 = j ^ (r & 7);
      gload16(A  + (size_t)(m0 + r) * K + kt + col8 * 8, lA + s * 8);
      gload16(Bt + (size_t)(n0 + r) * K + kt + col8 * 8, lB + s * 8);
    }
    __syncthreads();
#pragma unroll
    for (int ks = 0; ks < 2; ++ks) {
      short8 af[4], bfv[4];
#pragma unroll
      for (int t = 0; t < 4; ++t) {
        af[t]  = *(const short8*)(lA + (wm + t * 16 + l15) * 64 + ((ks * 4 + g) ^ sw) * 8);
        bfv[t] = *(const short8*)(lB + (wn + t * 16 + l15) * 64 + ((ks * 4 + g) ^ sw) * 8);
      }
#pragma unroll
      for (int mt = 0; mt < 4; ++mt)
#pragma unroll
        for (int nt = 0; nt < 4; ++nt)
          acc[mt][nt] = __builtin_amdgcn_mfma_f32_16x16x32_bf16(
              af[mt], bfv[nt], acc[mt][nt], 0, 0, 0);
    }
  }

#pragma unroll
  for (int mt = 0; mt < 4; ++mt)
#pragma unroll
    for (int nt = 0; nt < 4; ++nt)
#pragma unroll
      for (int r = 0; r < 4; ++r) {
        int row = m0 + wm + mt * 16 + g * 4 + r;
        int col = n0 + wn + nt * 16 + l15;
        float v = acc[mt][nt][r];
        if (c_fp32) ((float*)C)[(size_t)row * N + col] = v;
        else ((ushortT*)C)[(size_t)row * N + col] = f2bf(v);
      }
}

// ---------------- RoPE Q: QKVtmp cols [0,2048) -> (B,NH,S,HD) bf16 -------------
__global__ __launch_bounds__(256) void rope_q_kernel(
    const ushortT* __restrict__ QKVtmp, const float* __restrict__ cosT,
    const float* __restrict__ sinT, ushortT* __restrict__ Qr) {
  int idx = blockIdx.x * 256 + threadIdx.x;   // B*S*NH*64 total
  int d = idx & 63;
  int t = idx >> 6;          // (b*S+s)*NH + h
  int h = t & (NHD - 1);
  int bs = t >> 4;           // b*S + s
  int s = bs & (SEQ - 1);
  int b = bs >> 11;
  float c = cosT[s * HEADD + d], sn = sinT[s * HEADD + d];
  float q1 = bf2f(QKVtmp[(size_t)bs * QKVCOLS + h * HEADD + d]);
  float q2 = bf2f(QKVtmp[(size_t)bs * QKVCOLS + h * HEADD + d + 64]);
  size_t o = ((size_t)(b * NHD + h) * SEQ + s) * HEADD + d;
  Qr[o]      = f2bf(q1 * c - q2 * sn);
  Qr[o + 64] = f2bf(q2 * c + q1 * sn);
}

// ---------------- RoPE K: QKVtmp cols [2048,2560) -> (B,NKV,S,HD) bf16 ---------
__global__ __launch_bounds__(256) void rope_k_kernel(
    const ushortT* __restrict__ QKVtmp, const float* __restrict__ cosT,
    const float* __restrict__ sinT, ushortT* __restrict__ Kr) {
  int idx = blockIdx.x * 256 + threadIdx.x;   // B*S*NKV*64 total
  int d = idx & 63;
  int t = idx >> 6;          // (b*S+s)*NKV + kvh
  int kvh = t & (NKVH - 1);
  int bs = t >> 2;
  int s = bs & (SEQ - 1);
  int b = bs >> 11;
  float c = cosT[s * HEADD + d], sn = sinT[s * HEADD + d];
  float k1 = bf2f(QKVtmp[(size_t)bs * QKVCOLS + 2048 + kvh * HEADD + d]);
  float k2 = bf2f(QKVtmp[(size_t)bs * QKVCOLS + 2048 + kvh * HEADD + d + 64]);
  size_t o = ((size_t)(b * NKVH + kvh) * SEQ + s) * HEADD + d;
  Kr[o]      = f2bf(k1 * c - k2 * sn);
  Kr[o + 64] = f2bf(k2 * c + k1 * sn);
}

// ---------------- V relayout: QKVtmp cols [2560,3072) -> (B,NKV,HD,S) ----------
__global__ __launch_bounds__(256) void v_relayout_kernel(
    const ushortT* __restrict__ QKVtmp, ushortT* __restrict__ Vt) {
  __shared__ ushortT tile[32][33];
  int bk = blockIdx.z;             // b*NKV + kvh
  int b = bk >> 2, kvh = bk & 3;
  int s0 = blockIdx.x * 32, d0 = blockIdx.y * 32;
  int tx = threadIdx.x & 31, ty = threadIdx.x >> 5;
#pragma unroll
  for (int i = 0; i < 4; ++i) {
    int s = s0 + ty + i * 8;
    tile[ty + i * 8][tx] =
        QKVtmp[(size_t)(b * SEQ + s) * QKVCOLS + 2560 + kvh * HEADD + d0 + tx];
  }
  __syncthreads();
#pragma unroll
  for (int i = 0; i < 4; ++i) {
    int d = d0 + ty + i * 8;
    Vt[((size_t)bk * HEADD + d) * SEQ + s0 + tx] = tile[tx][ty + i * 8];
  }
}

// y -> (qi, chunk) tables. Triples {y, y+8, y+16} land on one CU (x-fastest
// dispatch, 768 blocks / 256 CUs); each triple sums to exactly 34 k-tile
// iterations, longest (16) dispatched first.
__device__ __constant__ const signed char QI_TAB[24] =
    {8,9,10,11,12,13,14,7, 15,15,6,14,5,13,4,12, 0,8,1,9,2,10,3,11};
__device__ __constant__ const signed char CH_TAB[24] =
    {0,0,0,0,0,0,0,0, 0,1,0,1,0,1,0,1, 0,1,0,1,0,1,0,1};

// ---------------- Flash attention (causal, GQA), BM=128/BN=64, split-K ---------
// grid (32=bh fast, 24=y). q-tiles 0..7: single block, writes Oa directly.
// q-tiles 8..15: split into chunk0 (keys 0..1023) and chunk1 (keys 1024..end);
// each writes unnormalized f32 partial O + per-row (m,l); merge kernel combines.
// Inner loop identical to the proven round-4 LDS-staged structure.
__global__ __launch_bounds__(256) void attn_kernel(
    const ushortT* __restrict__ Q,   // (B,NH,S,HD)
    const ushortT* __restrict__ Kg,  // (B,NKV,S,HD)
    const ushortT* __restrict__ Vg,  // (B,NKV,HD,S)
    ushortT* __restrict__ Oa,        // (B,S,NH*HD)
    float* __restrict__ PartA, float* __restrict__ PartB,
    float* __restrict__ Ml) {
  __shared__ __align__(16) ushortT lK[64 * 128];    // key x d, swizzled chunks
  __shared__ __align__(16) ushortT lV[128 * 64];    // d x key, swizzled chunks
  __shared__ __align__(16) ushortT lP[4 * 32 * 72]; // per-wave P (q x k), pad 72

  const int tid = threadIdx.x;
  const int w = tid >> 6, lane = tid & 63;
  const int g = lane >> 4, l15 = lane & 15;
  const int sw = l15 & 7;
  const int bh = blockIdx.x;
  const int b = bh >> 4, h = bh & 15;
  const int kvh = h >> 2;
  const int qi = QI_TAB[blockIdx.y];
  const int ch = CH_TAB[blockIdx.y];
  const int q0 = qi << 7;
  const int qw = q0 + w * 32;

  const float SC = 0.08838834764831845f * 1.4426950408889634f; // 1/sqrt(128)*log2e

  short8 qf[2][4];   // B-operand fragments of Q (q = qw + mt*16 + l15)
#pragma unroll
  for (int mt = 0; mt < 2; ++mt) {
    const ushortT* qp =
        Q + (((size_t)(b * NHD + h)) * SEQ + qw + mt * 16 + l15) * HEADD + g * 8;
#pragma unroll
    for (int ks = 0; ks < 4; ++ks) qf[mt][ks] = *(const short8*)(qp + ks * 32);
  }

  floatx4 o[2][8] = {};                       // O^T: col=q(l15), row=d(g*4+r)
  float m_s[2] = {-INFINITY, -INFINITY};
  float l_s[2] = {0.f, 0.f};

  const ushortT* kbase = Kg + ((size_t)(b * NKVH + kvh)) * SEQ * HEADD;
  const ushortT* vbase = Vg + ((size_t)(b * NKVH + kvh)) * HEADD * SEQ;
  ushortT* pw = lP + w * 32 * 72;

  const int ktend = 2 * qi + 2;
  const int kt0 = ch * 16;
  const int kt1 = (ktend < kt0 + 16) ? ktend : (kt0 + 16);
  for (int kt = kt0; kt < kt1; ++kt) {
    __syncthreads();
#pragma unroll
    for (int ii = 0; ii < 4; ++ii) {          // K tile: 64 keys x 128 d
      int s = ii * 256 + tid;
      int r = s >> 4, j = (s & 15) ^ (r & 7);
      gload16(kbase + (size_t)(kt * 64 + r) * HEADD + j * 8, lK + s * 8);
    }
#pragma unroll
    for (int ii = 0; ii < 4; ++ii) {          // V^T tile: 128 d x 64 keys
      int s = ii * 256 + tid;
      int r = s >> 3, j = (s & 7) ^ (r & 7);
      gload16(vbase + (size_t)r * SEQ + kt * 64 + j * 8, lV + s * 8);
    }
    __syncthreads();

    // diagonal k-tile is entirely above the causal line for lower-half waves
    if (kt == ktend - 1 && w < 2) continue;

    // S^T = K . Q^T : D col = q (l15), row = key (g*4+r), per nt key-16-block
    floatx4 sc[2][4] = {};
#pragma unroll
    for (int ks = 0; ks < 4; ++ks)
#pragma unroll
      for (int nt = 0; nt < 4; ++nt) {
        short8 kf = *(const short8*)(lK + (nt * 16 + l15) * 128 + ((ks * 4 + g) ^ sw) * 8);
        sc[0][nt] = __builtin_amdgcn_mfma_f32_16x16x32_bf16(kf, qf[0][ks], sc[0][nt], 0, 0, 0);
        sc[1][nt] = __builtin_amdgcn_mfma_f32_16x16x32_bf16(kf, qf[1][ks], sc[1][nt], 0, 0, 0);
      }

#pragma unroll
    for (int mt = 0; mt < 2; ++mt) {
      const int qsub = qw + mt * 16;               // + l15 per lane
      const bool needmask = (kt * 64 + 63) > qsub; // wave-uniform
      float ps[4][4];
      float mx = -INFINITY;
#pragma unroll
      for (int nt = 0; nt < 4; ++nt)
#pragma unroll
        for (int r = 0; r < 4; ++r) {
          float v = sc[mt][nt][r] * SC;
          if (needmask) {
            int kg = kt * 64 + nt * 16 + g * 4 + r;
            if (kg > qsub + l15) v = -INFINITY;
          }
          ps[nt][r] = v;
          mx = fmaxf(mx, v);
        }
      mx = fmaxf(mx, __shfl_xor(mx, 16));
      mx = fmaxf(mx, __shfl_xor(mx, 32));
      float mn = fmaxf(m_s[mt], mx);
      float alpha = __builtin_amdgcn_exp2f(m_s[mt] - mn);
      m_s[mt] = mn;
      float rs = 0.f;
#pragma unroll
      for (int nt = 0; nt < 4; ++nt) {
        ushort4v pk;
#pragma unroll
        for (int r = 0; r < 4; ++r) {
          float e = __builtin_amdgcn_exp2f(ps[nt][r] - mn);
          rs += e;
          ((ushortT*)&pk)[r] = f2bf(e);
        }
        // P[q_local][k]: row = mt*16+l15, k = nt*16 + g*4 .. +3 (b64 write)
        *(ushort4v*)(pw + (mt * 16 + l15) * 72 + nt * 16 + g * 4) = pk;
      }
      rs += __shfl_xor(rs, 16);
      rs += __shfl_xor(rs, 32);
      l_s[mt] = l_s[mt] * alpha + rs;
#pragma unroll
      for (int dt = 0; dt < 8; ++dt)
#pragma unroll
        for (int r = 0; r < 4; ++r) o[mt][dt][r] *= alpha;
    }

    // O^T += V^T . P^T   (A = V^T frag from lV, B = P^T frag from lP)
#pragma unroll
    for (int ks = 0; ks < 2; ++ks) {
      short8 bp0 = *(const short8*)(pw + l15 * 72 + ks * 32 + g * 8);
      short8 bp1 = *(const short8*)(pw + (16 + l15) * 72 + ks * 32 + g * 8);
#pragma unroll
      for (int dt = 0; dt < 8; ++dt) {
        short8 vf = *(const short8*)(lV + (dt * 16 + l15) * 64 + ((ks * 4 + g) ^ sw) * 8);
        o[0][dt] = __builtin_amdgcn_mfma_f32_16x16x32_bf16(vf, bp0, o[0][dt], 0, 0, 0);
        o[1][dt] = __builtin_amdgcn_mfma_f32_16x16x32_bf16(vf, bp1, o[1][dt], 0, 0, 0);
      }
    }
  }

  if (qi < 8) {
    // single-chunk: normalize and write Oa; q = qw+mt*16+l15, d = dt*16+g*4+r
#pragma unroll
    for (int mt = 0; mt < 2; ++mt) {
      float inv = 1.f / l_s[mt];
      int qg = qw + mt * 16 + l15;
#pragma unroll
      for (int dt = 0; dt < 8; ++dt) {
        ushort4v ov;
#pragma unroll
        for (int r = 0; r < 4; ++r) ((ushortT*)&ov)[r] = f2bf(o[mt][dt][r] * inv);
        *(ushort4v*)(Oa + (size_t)(b * SEQ + qg) * NQCOLS + h * HEADD + dt * 16 + g * 4) = ov;
      }
    }
  } else {
    // split: write unnormalized f32 partial O + per-row (m,l)
    int p = (bh * 8 + (qi - 8)) * 2 + ch;
    float* Pp = (p < 448) ? (PartA + (size_t)p * 16384)
                          : (PartB + (size_t)(p - 448) * 16384);
    float* mlp = Ml + p * 256;
#pragma unroll
    for (int mt = 0; mt < 2; ++mt) {
      int ql = w * 32 + mt * 16 + l15;
      if (g == 0) { mlp[ql * 2] = m_s[mt]; mlp[ql * 2 + 1] = l_s[mt]; }
#pragma unroll
      for (int dt = 0; dt < 8; ++dt)
        *(floatx4*)(Pp + ql * 128 + dt * 16 + g * 4) = o[mt][dt];
    }
  }
}

// ---------------- merge split-K partials -> Oa ----------------------------------
// grid (32 bh, 8 qih), 256 threads; thread handles 64 d of one q-row.
__global__ __launch_bounds__(256) void attn_merge_kernel(
    const float* __restrict__ PartA, const float* __restrict__ PartB,
    const float* __restrict__ Ml, ushortT* __restrict__ Oa) {
  int bh = blockIdx.x, qih = blockIdx.y;
  int b = bh >> 4, h = bh & 15;
  int p0 = (bh * 8 + qih) * 2, p1 = p0 + 1;
  const float* P0 = (p0 < 448) ? (PartA + (size_t)p0 * 16384)
                               : (PartB + (size_t)(p0 - 448) * 16384);
  const float* P1 = (p1 < 448) ? (PartA + (size_t)p1 * 16384)
                               : (PartB + (size_t)(p1 - 448) * 16384);
  int row = threadIdx.x >> 1, dh = (threadIdx.x & 1) * 64;
  float m0 = Ml[p0 * 256 + row * 2], l0 = Ml[p0 * 256 + row * 2 + 1];
  float m1 = Ml[p1 * 256 + row * 2], l1 = Ml[p1 * 256 + row * 2 + 1];
  float mm = fmaxf(m0, m1);
  float w0 = __builtin_amdgcn_exp2f(m0 - mm);
  float w1 = __builtin_amdgcn_exp2f(m1 - mm);
  float inv = 1.f / (w0 * l0 + w1 * l1);
  w0 *= inv; w1 *= inv;
  int q = (8 + qih) * 128 + row;
  ushortT* op = Oa + (size_t)(b * SEQ + q) * NQCOLS + h * HEADD + dh;
  const float* a = P0 + row * 128 + dh;
  const float* c = P1 + row * 128 + dh;
#pragma unroll
  for (int d = 0; d < 64; d += 4) {
    float4 va = *(const float4*)(a + d);
    float4 vc = *(const float4*)(c + d);
    ushort4v ov;
    ov.x = f2bf(w0 * va.x + w1 * vc.x);
    ov.y = f2bf(w0 * va.y + w1 * vc.y);
    ov.z = f2bf(w0 * va.z + w1 * vc.z);
    ov.w = f2bf(w0 * va.w + w1 * vc.w);
    *(ushort4v*)(op + d) = ov;
  }
}

extern "C" void kernel_launch(void* const* d_in, const int* in_sizes, int n_in,
                              void* d_out, int out_size, void* d_ws, size_t ws_size,
                              hipStream_t stream) {
  const float* x    = (const float*)d_in[0];
  const float* cosT = (const float*)d_in[1];
  const float* sinT = (const float*)d_in[2];
  const float* Wq   = (const float*)d_in[3];
  const float* Wkv  = (const float*)d_in[4];
  const float* Wo   = (const float*)d_in[5];

  char* ws = (char*)d_ws;
  // workspace layout (bytes)
  ushortT* x_bf   = (ushortT*)(ws + 0);          // 16777216 (dead after QKV GEMM)
  ushortT* Wqkvt  = (ushortT*)(ws + 16777216);   // 12582912 (dead after QKV GEMM)
  ushortT* Wot    = (ushortT*)(ws + 29360128);   //  8388608 (live until O-proj)
  ushortT* QKVtmp = (ushortT*)(ws + 37748736);   // 25165824 (dead after rope/relayout)
  ushortT* Qr     = (ushortT*)(ws + 62914560);   // 16777216
  ushortT* Kr     = (ushortT*)(ws + 79691776);   //  4194304
  ushortT* Vt     = (ushortT*)(ws + 83886080);   //  4194304
  ushortT* Oattn  = QKVtmp;                      // 16 MB alias of QKVtmp[0:16M]
  // split-K partials (alias dead regions during attention):
  float* PartA = (float*)(ws + 0);               // partials 0..447 (28 MB = x_bf+Wqkvt)
  float* PartB = (float*)(ws + 54525952);        // partials 448..511 (4 MB, QKVtmp tail)
  float* Ml    = (float*)(ws + 58720256);        // 512 x 128 x (m,l) f32 = 512 KB

  // 1) casts / weight transposes (Wq|Wkv stacked into one N x K operand)
  cast_bf16_kernel<<<8192, 256, 0, stream>>>(x, x_bf, (MROWS * HDIM) / 4);
  transpose_cast_kernel<<<dim3(64, 64), 256, 0, stream>>>(Wq, Wqkvt, HDIM, NQCOLS);
  transpose_cast_kernel<<<dim3(32, 64), 256, 0, stream>>>(Wkv, Wqkvt + 2048 * 2048, HDIM, 1024);
  transpose_cast_kernel<<<dim3(64, 64), 256, 0, stream>>>(Wo, Wot, NQCOLS, HDIM);

  // 2) fused QKV projection: (4096 x 2048) x (2048 x 3072) -> 768 blocks, 3/CU
  gemm_bt_kernel<<<dim3(24, 32), 256, 0, stream>>>(x_bf, Wqkvt, QKVtmp, MROWS, QKVCOLS, HDIM, 0);

  // 3) rope + relayout
  rope_q_kernel<<<16384, 256, 0, stream>>>(QKVtmp, cosT, sinT, Qr);
  rope_k_kernel<<<4096, 256, 0, stream>>>(QKVtmp, cosT, sinT, Kr);
  v_relayout_kernel<<<dim3(64, 4, 8), 256, 0, stream>>>(QKVtmp, Vt);

  // 4) attention, split-K: 768 blocks = 3/CU, 34 iters/CU, then merge
  attn_kernel<<<dim3(32, 24), 256, 0, stream>>>(Qr, Kr, Vt, Oattn, PartA, PartB, Ml);
  attn_merge_kernel<<<dim3(32, 8), 256, 0, stream>>>(PartA, PartB, Ml, Oattn);

  // 5) output projection (fp32 out)
  gemm_bt_kernel<<<dim3(16, 32), 256, 0, stream>>>(Oattn, Wot, d_out, MROWS, HDIM, NQCOLS, 1);
}